// Round 2
// baseline (208.938 us; speedup 1.0000x reference)
//
#include <hip/hip_runtime.h>
#include <hip/hip_bf16.h>
#include <math.h>

#define NB 65536
#define DIN 1024
#define NQ 64
#define DOUT 1024

typedef __attribute__((ext_vector_type(8))) short bf16x8;
typedef __attribute__((ext_vector_type(4))) float f32x4;

__device__ __forceinline__ unsigned short f2bf(float f) {
    union { float f; unsigned u; } v; v.f = f;
    unsigned r = (v.u + 0x7fffu + ((v.u >> 16) & 1u)) >> 16;
    return (unsigned short)r;
}

// ---- kP: precompute bf16 weights + per-q constants --------------------------
__global__ __launch_bounds__(256) void kP(const float* __restrict__ W_in,
                                          const float* __restrict__ W_out,
                                          const float* __restrict__ qp,
                                          unsigned short* __restrict__ Wb,
                                          unsigned short* __restrict__ Wob,
                                          float* __restrict__ cp0,
                                          float* __restrict__ cq) {
    int i = blockIdx.x * 256 + threadIdx.x;
    if (i < NQ * DIN)  Wb[i]  = f2bf(W_in[i]);
    if (i < DOUT * NQ) Wob[i] = f2bf(W_out[i]);
    if (i < NQ) {
        cp0[i] = cosf(qp[i * 3 + 0]);
        cq[i]  = sinf(qp[i * 3 + 1]) * cosf(qp[i * 3 + 2]);
    }
}

// ---- kF: fused  out = state(x) @ W_out.T + b_out ----------------------------
// 1024 blocks x 256 threads (4 waves). Block owns 64 batch rows, wave owns 16.
// Phase A: GEMM1 (K=1024) + quantum epilogue -> per-wave 16x64 bf16 tile in LDS.
// Phase B: GEMM2 (K=64) reading A-fragments from LDS, W_out from L2, f32 out.
__global__ __launch_bounds__(256) void kF(const float* __restrict__ x,
                                          const unsigned short* __restrict__ Wb,
                                          const float* __restrict__ b_in,
                                          const float* __restrict__ cp0,
                                          const float* __restrict__ cq,
                                          const unsigned short* __restrict__ Wob,
                                          const float* __restrict__ b_out,
                                          float* __restrict__ out) {
    // stride 72 shorts = 144 B -> fragment reads alias banks only 2-way (free)
    __shared__ unsigned short st[4][16][72];

    const int wave = threadIdx.x >> 6;
    const int lane = threadIdx.x & 63;
    const int r  = lane & 15;   // tile row (phase A: batch row; also out-col mod 16)
    const int kg = lane >> 4;   // k-group
    const int row0 = blockIdx.x * 64 + wave * 16;

    // ---------------- Phase A: GEMM1 ----------------
    const float* xrow = x + (size_t)(row0 + r) * DIN + kg * 8;

    f32x4 acc[4] = {f32x4{0,0,0,0}, f32x4{0,0,0,0}, f32x4{0,0,0,0}, f32x4{0,0,0,0}};

    for (int k0 = 0; k0 < DIN; k0 += 32) {
        float4 a0 = *(const float4*)(xrow + k0);
        float4 a1 = *(const float4*)(xrow + k0 + 4);
        bf16x8 a;
        a[0] = (short)f2bf(a0.x); a[1] = (short)f2bf(a0.y);
        a[2] = (short)f2bf(a0.z); a[3] = (short)f2bf(a0.w);
        a[4] = (short)f2bf(a1.x); a[5] = (short)f2bf(a1.y);
        a[6] = (short)f2bf(a1.z); a[7] = (short)f2bf(a1.w);
        #pragma unroll
        for (int n = 0; n < 4; n++) {
            bf16x8 b = *(const bf16x8*)(Wb + (size_t)(n * 16 + r) * DIN + k0 + kg * 8);
            acc[n] = __builtin_amdgcn_mfma_f32_16x16x32_bf16(a, b, acc[n], 0, 0, 0);
        }
    }

    // Quantum epilogue (hw transcendentals), write bf16 state tile to LDS.
    // D layout: col q = n*16+r, row = kg*4+i.
    #pragma unroll
    for (int n = 0; n < 4; n++) {
        int q = n * 16 + r;
        float bi = b_in[q], c0 = cp0[q], c1 = cq[q];
        #pragma unroll
        for (int i = 0; i < 4; i++) {
            float a  = acc[n][i] + bi;
            // tanh(a) = 1 - 2/(exp2(2a*log2e)+1)
            float e2 = __builtin_amdgcn_exp2f(a * 2.8853900817779268f);
            float th = 1.0f - 2.0f * __builtin_amdgcn_rcpf(e2 + 1.0f);
            // cos(th * pi/2) = cos(2*pi * th/4)  (v_cos takes revolutions)
            float s  = __builtin_amdgcn_cosf(th * 0.25f) * c0 + c1;
            st[wave][kg * 4 + i][q] = f2bf(s);
        }
    }

    __syncthreads();

    // ---------------- Phase B: GEMM2 ----------------
    // A-fragment: lane row = r (wave-local), k(=q) = kg*8+j  /  +32 for a1
    bf16x8 sa0 = *(const bf16x8*)&st[wave][r][kg * 8];
    bf16x8 sa1 = *(const bf16x8*)&st[wave][r][32 + kg * 8];

    #pragma unroll
    for (int c = 0; c < 4; c++) {          // 4 chunks of 256 out-cols
        f32x4 acc2[16];
        #pragma unroll
        for (int n = 0; n < 16; n++) acc2[n] = f32x4{0, 0, 0, 0};

        #pragma unroll
        for (int n = 0; n < 16; n++) {
            int col = c * 256 + n * 16 + r;
            const unsigned short* wp = Wob + (size_t)col * NQ + kg * 8;
            bf16x8 b0 = *(const bf16x8*)(wp);
            bf16x8 b1 = *(const bf16x8*)(wp + 32);
            acc2[n] = __builtin_amdgcn_mfma_f32_16x16x32_bf16(sa0, b0, acc2[n], 0, 0, 0);
            acc2[n] = __builtin_amdgcn_mfma_f32_16x16x32_bf16(sa1, b1, acc2[n], 0, 0, 0);
        }

        #pragma unroll
        for (int n = 0; n < 16; n++) {
            int col = c * 256 + n * 16 + r;
            float bo = b_out[col];
            #pragma unroll
            for (int i = 0; i < 4; i++) {
                __builtin_nontemporal_store(acc2[n][i] + bo,
                    &out[(size_t)(row0 + kg * 4 + i) * DOUT + col]);
            }
        }
    }
}

extern "C" void kernel_launch(void* const* d_in, const int* in_sizes, int n_in,
                              void* d_out, int out_size, void* d_ws, size_t ws_size,
                              hipStream_t stream) {
    const float* x    = (const float*)d_in[0];
    const float* W_in = (const float*)d_in[1];
    const float* b_in = (const float*)d_in[2];
    const float* qp   = (const float*)d_in[3];
    const float* W_out= (const float*)d_in[4];
    const float* b_out= (const float*)d_in[5];
    float* out = (float*)d_out;

    char* ws = (char*)d_ws;
    unsigned short* Wb  = (unsigned short*)(ws);            // 128 KB
    unsigned short* Wob = (unsigned short*)(ws + 131072);   // 128 KB
    float*          cp0 = (float*)(ws + 262144);            // 256 B
    float*          cq  = (float*)(ws + 262400);            // 256 B

    kP<<<(NQ * DIN + 255) / 256, 256, 0, stream>>>(W_in, W_out, qp, Wb, Wob, cp0, cq);
    kF<<<NB / 64, 256, 0, stream>>>(x, Wb, b_in, cp0, cq, Wob, b_out, out);
}